// Round 5
// baseline (1140.813 us; speedup 1.0000x reference)
//
#include <hip/hip_runtime.h>
#include <math.h>

// ---------------------------------------------------------------------------
// MultiheadAttention fwd, MI355X. B=8 N=1024 E=768 H=12 D=64.
//   K0 split_convert : X, Wq/k/v/o fp32 -> (hi,lo) bf16 pairs in ws
//   K1 qkv_gemm      : split-bf16 MFMA; emits Q/K (hi,lo bf16, [head][n][d])
//                      and V transposed ([head][d][n]); q scaled by 1/8
//   K2 attn_mfma     : flash attention, split-bf16 MFMA QK^T + PV,
//                      K/V/bias streamed from global (L2-resident, XCD-pinned)
//   K3 out_gemm      : split-bf16 MFMA, out = attn@Wo.T + bo
// Split-bf16: x*w ~= xh*wh + xh*wl + xl*wh, error ~1e-4 rel over K=768.
// ---------------------------------------------------------------------------

namespace {

constexpr int kB = 8, kN = 1024, kE = 768, kH = 12, kD = 64;
constexpr int kM = kB * kN;          // 8192 rows
constexpr int kNX = kM * kE;         // 6,291,456 elems (X, attn, also per-QKV)
constexpr int kNW = kE * kE;         // 589,824 elems per weight
constexpr int kTot = kNX + 4 * kNW;  // 8,650,752

typedef short bf16x8 __attribute__((ext_vector_type(8)));
typedef float f32x4 __attribute__((ext_vector_type(4)));

__device__ __forceinline__ ushort f2bf(float x) {
  uint u = __float_as_uint(x);
  u += 0x7fffu + ((u >> 16) & 1u);  // RNE
  return (ushort)(u >> 16);
}
__device__ __forceinline__ float bf2f(ushort h) {
  return __uint_as_float(((uint)h) << 16);
}

// ---------------- K0: fp32 -> (hi, lo) bf16 split (X + 4 weights) ----------
__global__ __launch_bounds__(256)
void split_convert(const float* __restrict__ X, const float* __restrict__ Wq,
                   const float* __restrict__ Wk, const float* __restrict__ Wv,
                   const float* __restrict__ Wo, ushort* __restrict__ Xh,
                   ushort* __restrict__ Xl, ushort* __restrict__ Wh,
                   ushort* __restrict__ Wl) {
  const int gid = blockIdx.x * 256 + threadIdx.x;
  const int i4 = gid * 4;
  if (i4 >= kTot) return;
  const float* s;
  ushort *dh, *dl;
  if (i4 < kNX) {
    s = X + i4;
    dh = Xh + i4;
    dl = Xl + i4;
  } else {
    const int j = i4 - kNX;
    const int w = j / kNW;
    const int o = j - w * kNW;
    s = (w == 0) ? Wq + o : (w == 1) ? Wk + o : (w == 2) ? Wv + o : Wo + o;
    dh = Wh + j;
    dl = Wl + j;
  }
  const float4 v = *(const float4*)s;
  ushort4 h, l;
  h.x = f2bf(v.x);
  h.y = f2bf(v.y);
  h.z = f2bf(v.z);
  h.w = f2bf(v.w);
  l.x = f2bf(v.x - bf2f(h.x));
  l.y = f2bf(v.y - bf2f(h.y));
  l.z = f2bf(v.z - bf2f(h.z));
  l.w = f2bf(v.w - bf2f(h.w));
  *(ushort4*)dh = h;
  *(ushort4*)dl = l;
}

// ---------------- shared MFMA GEMM core (HW-validated round 2) -------------
// C(128x128) = A(128xK) . B(NxK)^T tile, split-bf16 3-pass.
// 4 waves (2x2), wave tile 64x64 = 4x4 frags of mfma_f32_16x16x32_bf16.
// A/B lane: row|col = lane&15, k = (lane>>4)*8+e; D: col=lane&15,
// row=(lane>>4)*4+reg. LDS pitch 40 ushorts: b128 reads conflict-free.
template <typename EPI>
__device__ __forceinline__ void gemm_core(const ushort* __restrict__ Ahg,
                                          const ushort* __restrict__ Alg,
                                          const ushort* __restrict__ Bhg,
                                          const ushort* __restrict__ Blg,
                                          int m0, int o0, EPI epi) {
  __shared__ ushort Ah[128][40], Al[128][40], Bh[128][40], Bl[128][40];
  const int tid = threadIdx.x;
  const int wid = tid >> 6, lane = tid & 63;
  const int wm = wid >> 1, wn = wid & 1;
  const int g = lane >> 4, lr = lane & 15;

  f32x4 acc[4][4];
#pragma unroll
  for (int i = 0; i < 4; ++i)
#pragma unroll
    for (int j = 0; j < 4; ++j) acc[i][j] = (f32x4)0.f;

  for (int k0 = 0; k0 < kE; k0 += 32) {
#pragma unroll
    for (int p = 0; p < 4; ++p) {
      const int f = tid + p * 256;
      const int m = f >> 3, kq = f & 7;
      const int ga = (m0 + m) * kE + k0 + kq * 4;
      const int gb = (o0 + m) * kE + k0 + kq * 4;
      *(uint2*)&Ah[m][kq * 4] = *(const uint2*)&Ahg[ga];
      *(uint2*)&Al[m][kq * 4] = *(const uint2*)&Alg[ga];
      *(uint2*)&Bh[m][kq * 4] = *(const uint2*)&Bhg[gb];
      *(uint2*)&Bl[m][kq * 4] = *(const uint2*)&Blg[gb];
    }
    __syncthreads();

    bf16x8 ah[4], al[4];
#pragma unroll
    for (int mi = 0; mi < 4; ++mi) {
      const int ar = wm * 64 + mi * 16 + lr;
      ah[mi] = *reinterpret_cast<const bf16x8*>(&Ah[ar][g * 8]);
      al[mi] = *reinterpret_cast<const bf16x8*>(&Al[ar][g * 8]);
    }
#pragma unroll
    for (int nj = 0; nj < 4; ++nj) {
      const int br = wn * 64 + nj * 16 + lr;
      const bf16x8 bh = *reinterpret_cast<const bf16x8*>(&Bh[br][g * 8]);
      const bf16x8 bl = *reinterpret_cast<const bf16x8*>(&Bl[br][g * 8]);
#pragma unroll
      for (int mi = 0; mi < 4; ++mi) {
        acc[mi][nj] = __builtin_amdgcn_mfma_f32_16x16x32_bf16(ah[mi], bh,
                                                              acc[mi][nj], 0, 0, 0);
        acc[mi][nj] = __builtin_amdgcn_mfma_f32_16x16x32_bf16(ah[mi], bl,
                                                              acc[mi][nj], 0, 0, 0);
        acc[mi][nj] = __builtin_amdgcn_mfma_f32_16x16x32_bf16(al[mi], bh,
                                                              acc[mi][nj], 0, 0, 0);
      }
    }
    __syncthreads();
  }

#pragma unroll
  for (int nj = 0; nj < 4; ++nj) {
    const int o = o0 + wn * 64 + nj * 16 + lr;
#pragma unroll
    for (int mi = 0; mi < 4; ++mi) {
      const int mbase = m0 + wm * 64 + mi * 16 + g * 4;
#pragma unroll
      for (int r = 0; r < 4; ++r) epi(mbase + r, o, acc[mi][nj][r]);
    }
  }
}

// ---------------- K1: fused QKV projection ---------------------------------
__global__ __launch_bounds__(256)
void qkv_gemm(const ushort* __restrict__ Xh, const ushort* __restrict__ Xl,
              const ushort* __restrict__ Wh, const ushort* __restrict__ Wl,
              const float* __restrict__ bq, const float* __restrict__ bk,
              const float* __restrict__ bv, ushort* __restrict__ Qh,
              ushort* __restrict__ Ql, ushort* __restrict__ Kh,
              ushort* __restrict__ Kl, ushort* __restrict__ Vth,
              ushort* __restrict__ Vtl) {
  const int z = blockIdx.z;
  const ushort* WhZ = Wh + (size_t)z * kNW;
  const ushort* WlZ = Wl + (size_t)z * kNW;
  const float* bb = (z == 0) ? bq : (z == 1) ? bk : bv;

  gemm_core(Xh, Xl, WhZ, WlZ, blockIdx.x * 128, blockIdx.y * 128,
            [=](int m, int o, float v) {
              const int bi = m >> 10, n = m & 1023;
              const int h = o >> 6, d = o & 63;
              const int head = bi * kH + h;
              float val = v + bb[o];
              if (z == 0) val *= 0.125f;  // d^-0.5
              const ushort hi = f2bf(val);
              const ushort lo = f2bf(val - bf2f(hi));
              if (z == 2) {  // V stored transposed [head][d][n]
                const size_t idx = ((size_t)head * kD + d) * kN + n;
                Vth[idx] = hi;
                Vtl[idx] = lo;
              } else {
                const size_t idx = ((size_t)head * kN + n) * kD + d;
                if (z == 0) {
                  Qh[idx] = hi;
                  Ql[idx] = lo;
                } else {
                  Kh[idx] = hi;
                  Kl[idx] = lo;
                }
              }
            });
}

// ---------------- K2: MFMA flash attention ---------------------------------
// Grid 1536 linear, bijective head-chunked swizzle: all 16 q-blocks of a head
// land on one XCD (K/V stay L2-resident). Block = 4 waves; wave owns 16 q rows.
// K/V/bias B-frags streamed from global; P via per-wave LDS (pitch 68 uints,
// (hi|lo<<16) packed). Softmax wave-local via shfl_xor within 16-lane groups.
__global__ __launch_bounds__(256, 2)
void attn_mfma(const ushort* __restrict__ Qhg, const ushort* __restrict__ Qlg,
               const ushort* __restrict__ Khg, const ushort* __restrict__ Klg,
               const ushort* __restrict__ Vth, const ushort* __restrict__ Vtl,
               const float* __restrict__ bias, ushort* __restrict__ AoH,
               ushort* __restrict__ AoL) {
  __shared__ uint Plds[4][16 * 68];

  const int lb = blockIdx.x;
  const int xcd = lb & 7;
  const int idx = lb >> 3;       // 0..191
  const int lh = idx >> 4;       // 0..11
  const int qb = idx & 15;       // 0..15
  const int head = lh * 8 + xcd; // 0..95, bijective
  const int n0 = qb * 64;

  const int tid = threadIdx.x;
  const int w = tid >> 6, lane = tid & 63;
  const int g = lane >> 4, c = lane & 15;

  const size_t qkoff = (size_t)head * kN * kD;
  const float* __restrict__ biash = bias + (size_t)head * kN * kN;
  uint* __restrict__ Pw = &Plds[w][0];

  // Q A-frags: rows n0 + w*16 + c, k = d (2 ksteps of 32)
  bf16x8 qah[2], qal[2];
#pragma unroll
  for (int ks = 0; ks < 2; ++ks) {
    const size_t qi = qkoff + (size_t)(n0 + w * 16 + c) * kD + ks * 32 + g * 8;
    qah[ks] = *reinterpret_cast<const bf16x8*>(&Qhg[qi]);
    qal[ks] = *reinterpret_cast<const bf16x8*>(&Qlg[qi]);
  }

  f32x4 o[4];
#pragma unroll
  for (int fd = 0; fd < 4; ++fd) o[fd] = (f32x4)0.f;
  float m_old[4] = {-__builtin_inff(), -__builtin_inff(), -__builtin_inff(),
                    -__builtin_inff()};
  float lsum[4] = {0.f, 0.f, 0.f, 0.f};

  for (int t = 0; t < 16; ++t) {
    const int kvb = t * 64;

    // bias tile (issued early; consumed after QK^T)
    float bld[4][4];
#pragma unroll
    for (int j = 0; j < 4; ++j)
#pragma unroll
      for (int r = 0; r < 4; ++r)
        bld[j][r] = biash[(size_t)(n0 + w * 16 + g * 4 + r) * kN + kvb +
                          j * 16 + c];

    // S = Q K^T (split-bf16 3-pass), B-frags streamed from global
    f32x4 s[4];
#pragma unroll
    for (int j = 0; j < 4; ++j) s[j] = (f32x4)0.f;
#pragma unroll
    for (int j = 0; j < 4; ++j) {
#pragma unroll
      for (int ks = 0; ks < 2; ++ks) {
        const size_t ki =
            qkoff + (size_t)(kvb + j * 16 + c) * kD + ks * 32 + g * 8;
        const bf16x8 kbh = *reinterpret_cast<const bf16x8*>(&Khg[ki]);
        const bf16x8 kbl = *reinterpret_cast<const bf16x8*>(&Klg[ki]);
        s[j] = __builtin_amdgcn_mfma_f32_16x16x32_bf16(qah[ks], kbh, s[j], 0, 0, 0);
        s[j] = __builtin_amdgcn_mfma_f32_16x16x32_bf16(qal[ks], kbh, s[j], 0, 0, 0);
        s[j] = __builtin_amdgcn_mfma_f32_16x16x32_bf16(qah[ks], kbl, s[j], 0, 0, 0);
      }
    }
#pragma unroll
    for (int j = 0; j < 4; ++j)
#pragma unroll
      for (int r = 0; r < 4; ++r) s[j][r] += bld[j][r];

    // online softmax (wave-local; rows live in 16-lane groups)
    float mt[4];
#pragma unroll
    for (int r = 0; r < 4; ++r)
      mt[r] = fmaxf(fmaxf(s[0][r], s[1][r]), fmaxf(s[2][r], s[3][r]));
#pragma unroll
    for (int mask = 1; mask < 16; mask <<= 1)
#pragma unroll
      for (int r = 0; r < 4; ++r)
        mt[r] = fmaxf(mt[r], __shfl_xor(mt[r], mask, 16));
    float sc[4];
#pragma unroll
    for (int r = 0; r < 4; ++r) {
      const float mn = fmaxf(m_old[r], mt[r]);
      sc[r] = __expf(m_old[r] - mn);  // 0 on first tile
      m_old[r] = mn;
    }
    float rt[4] = {0.f, 0.f, 0.f, 0.f};
#pragma unroll
    for (int j = 0; j < 4; ++j)
#pragma unroll
      for (int r = 0; r < 4; ++r) {
        const float p = __expf(s[j][r] - m_old[r]);
        s[j][r] = p;
        rt[r] += p;
      }
#pragma unroll
    for (int mask = 1; mask < 16; mask <<= 1)
#pragma unroll
      for (int r = 0; r < 4; ++r) rt[r] += __shfl_xor(rt[r], mask, 16);
#pragma unroll
    for (int r = 0; r < 4; ++r) lsum[r] = lsum[r] * sc[r] + rt[r];
#pragma unroll
    for (int fd = 0; fd < 4; ++fd)
#pragma unroll
      for (int r = 0; r < 4; ++r) o[fd][r] *= sc[r];

    // P -> (hi|lo<<16) packed LDS, D-layout rows -> A-layout rows
#pragma unroll
    for (int j = 0; j < 4; ++j)
#pragma unroll
      for (int r = 0; r < 4; ++r) {
        const float p = s[j][r];
        const ushort hi = f2bf(p);
        const ushort lo = f2bf(p - bf2f(hi));
        Pw[(g * 4 + r) * 68 + j * 16 + c] = (uint)hi | ((uint)lo << 16);
      }

    // same-wave LDS write->transposed-read: compiler+HW fence (cheap: the
    // lgkmcnt(0) would be paid before the MFMA consumes the reads anyway)
    __threadfence_block();

    // O += P V (split-bf16 3-pass), V B-frags streamed from global (Vt)
#pragma unroll
    for (int ks = 0; ks < 2; ++ks) {
      const uint4 r0 = *(const uint4*)&Pw[c * 68 + ks * 32 + g * 8];
      const uint4 r1 = *(const uint4*)&Pw[c * 68 + ks * 32 + g * 8 + 4];
      union {
        uint u[4];
        bf16x8 v;
      } ph, pl;
      ph.u[0] = (r0.x & 0xffffu) | (r0.y << 16);
      pl.u[0] = (r0.x >> 16) | (r0.y & 0xffff0000u);
      ph.u[1] = (r0.z & 0xffffu) | (r0.w << 16);
      pl.u[1] = (r0.z >> 16) | (r0.w & 0xffff0000u);
      ph.u[2] = (r1.x & 0xffffu) | (r1.y << 16);
      pl.u[2] = (r1.x >> 16) | (r1.y & 0xffff0000u);
      ph.u[3] = (r1.z & 0xffffu) | (r1.w << 16);
      pl.u[3] = (r1.z >> 16) | (r1.w & 0xffff0000u);
#pragma unroll
      for (int fd = 0; fd < 4; ++fd) {
        const size_t vi =
            ((size_t)head * kD + fd * 16 + c) * kN + kvb + ks * 32 + g * 8;
        const bf16x8 vbh = *reinterpret_cast<const bf16x8*>(&Vth[vi]);
        const bf16x8 vbl = *reinterpret_cast<const bf16x8*>(&Vtl[vi]);
        o[fd] = __builtin_amdgcn_mfma_f32_16x16x32_bf16(ph.v, vbh, o[fd], 0, 0, 0);
        o[fd] = __builtin_amdgcn_mfma_f32_16x16x32_bf16(pl.v, vbh, o[fd], 0, 0, 0);
        o[fd] = __builtin_amdgcn_mfma_f32_16x16x32_bf16(ph.v, vbl, o[fd], 0, 0, 0);
      }
    }
  }

  // epilogue: normalize, split to (hi,lo) bf16, write [B,N,E]
  const int bb_ = head / kH, hh = head - bb_ * kH;
  float inv[4];
#pragma unroll
  for (int r = 0; r < 4; ++r) inv[r] = 1.0f / lsum[r];
#pragma unroll
  for (int fd = 0; fd < 4; ++fd)
#pragma unroll
    for (int r = 0; r < 4; ++r) {
      const float val = o[fd][r] * inv[r];
      const ushort hi = f2bf(val);
      const ushort lo = f2bf(val - bf2f(hi));
      const size_t oi = ((size_t)bb_ * kN + n0 + w * 16 + g * 4 + r) * kE +
                        hh * kD + fd * 16 + c;
      AoH[oi] = hi;
      AoL[oi] = lo;
    }
}

// ---------------- K3: output projection ------------------------------------
__global__ __launch_bounds__(256)
void out_gemm(const ushort* __restrict__ Ahg, const ushort* __restrict__ Alg,
              const ushort* __restrict__ Wh, const ushort* __restrict__ Wl,
              const float* __restrict__ bo, float* __restrict__ Y) {
  gemm_core(Ahg, Alg, Wh, Wl, blockIdx.x * 128, blockIdx.y * 128,
            [=](int m, int o, float v) { Y[(size_t)m * kE + o] = v + bo[o]; });
}

}  // namespace

// ---------------------------------------------------------------------------
extern "C" void kernel_launch(void* const* d_in, const int* in_sizes, int n_in,
                              void* d_out, int out_size, void* d_ws,
                              size_t ws_size, hipStream_t stream) {
  (void)in_sizes;
  (void)n_in;
  (void)out_size;
  (void)ws_size;
  const float* x = (const float*)d_in[0];
  const float* bias = (const float*)d_in[1];
  const float* Wq = (const float*)d_in[2];
  const float* bq = (const float*)d_in[3];
  const float* Wk = (const float*)d_in[4];
  const float* bk = (const float*)d_in[5];
  const float* Wv = (const float*)d_in[6];
  const float* bv = (const float*)d_in[7];
  const float* Wo = (const float*)d_in[8];
  const float* bo = (const float*)d_in[9];
  float* out = (float*)d_out;

  // ws: 10*kNX + 8*kNW ushorts = 135.3 MB
  ushort* p = (ushort*)d_ws;
  ushort* QhA = p;
  p += kNX;
  ushort* QlA = p;
  p += kNX;
  ushort* KhA = p;
  p += kNX;
  ushort* KlA = p;
  p += kNX;
  ushort* VthA = p;
  p += kNX;
  ushort* VtlA = p;
  p += kNX;
  ushort* Xh = p;
  p += kNX;
  ushort* Xl = p;
  p += kNX;
  ushort* Whs = p;
  p += 4 * (size_t)kNW;
  ushort* Wls = p;
  p += 4 * (size_t)kNW;
  ushort* AttnH = p;
  p += kNX;
  ushort* AttnL = p;

  split_convert<<<kTot / 1024, 256, 0, stream>>>(x, Wq, Wk, Wv, Wo, Xh, Xl,
                                                 Whs, Wls);

  dim3 g1(kM / 128, kE / 128, 3);
  qkv_gemm<<<g1, 256, 0, stream>>>(Xh, Xl, Whs, Wls, bq, bk, bv, QhA, QlA,
                                   KhA, KlA, VthA, VtlA);

  attn_mfma<<<1536, 256, 0, stream>>>(QhA, QlA, KhA, KlA, VthA, VtlA, bias,
                                      AttnH, AttnL);

  dim3 g3(kM / 128, kE / 128);
  out_gemm<<<g3, 256, 0, stream>>>(AttnH, AttnL, Whs + 3 * (size_t)kNW,
                                   Wls + 3 * (size_t)kNW, bo, out);
}